// Round 1
// baseline (3323.024 us; speedup 1.0000x reference)
//
#include <hip/hip_runtime.h>
#include <hip/hip_bf16.h>
#include <cstdint>

#define N_NODES 50000
#define N_PAIRS 800000
#define NHEADS 4
#define NF 256
#define HD 64

typedef unsigned short ushort_t;

__device__ __forceinline__ float bfu(unsigned int lo16) {
    union { unsigned int u; float f; } c; c.u = lo16 << 16; return c.f;
}
__device__ __forceinline__ ushort_t f2bf(float f) {
    union { float f; unsigned int u; } c; c.f = f;
    unsigned int u = c.u;
    unsigned int r = (u + 0x7fffu + ((u >> 16) & 1u)) >> 16;
    return (ushort_t)r;
}

// ---------------- Projection: q,k,v = per-head x @ W^T (fp32 in, bf16 out) --------
// block = 256 threads (wave = head, lane = output elem e).
// Each thread holds its 3x64 fp32 weight rows in VGPRs; x staged via LDS.
__global__ __launch_bounds__(256, 2) void proj_kernel(
    const float* __restrict__ x,
    const float* __restrict__ Wq, const float* __restrict__ Wk,
    const float* __restrict__ Wv,
    ushort_t* __restrict__ q, ushort_t* __restrict__ k, ushort_t* __restrict__ v)
{
    const int t = threadIdx.x;
    const int h = t >> 6;
    const int e = t & 63;

    float wq[64], wk[64], wv[64];
    {
        const float4* rq = (const float4*)(Wq + (size_t)(h * 64 + e) * 64);
        const float4* rk = (const float4*)(Wk + (size_t)(h * 64 + e) * 64);
        const float4* rv = (const float4*)(Wv + (size_t)(h * 64 + e) * 64);
#pragma unroll
        for (int r = 0; r < 16; ++r) {
            float4 a = rq[r];
            wq[r*4+0]=a.x; wq[r*4+1]=a.y; wq[r*4+2]=a.z; wq[r*4+3]=a.w;
            float4 b = rk[r];
            wk[r*4+0]=b.x; wk[r*4+1]=b.y; wk[r*4+2]=b.z; wk[r*4+3]=b.w;
            float4 c = rv[r];
            wv[r*4+0]=c.x; wv[r*4+1]=c.y; wv[r*4+2]=c.z; wv[r*4+3]=c.w;
        }
    }

    __shared__ float xs[8][256];     // 8 nodes x 256 features
    const int n0 = blockIdx.x * 8;   // 50000 / 8 = 6250 exactly
    {
        const float4* src = (const float4*)(x + (size_t)n0 * 256);
        float4* dst = (float4*)(&xs[0][0]);
        dst[t]       = src[t];
        dst[t + 256] = src[t + 256];
    }
    __syncthreads();

#pragma unroll 1
    for (int s = 0; s < 8; ++s) {
        const float4* xr = (const float4*)(&xs[s][h * 64]);
        float aq = 0.f, ak = 0.f, av = 0.f;
#pragma unroll
        for (int d4 = 0; d4 < 16; ++d4) {
            float4 xv = xr[d4];
            aq = fmaf(wq[d4*4+0], xv.x, aq); ak = fmaf(wk[d4*4+0], xv.x, ak); av = fmaf(wv[d4*4+0], xv.x, av);
            aq = fmaf(wq[d4*4+1], xv.y, aq); ak = fmaf(wk[d4*4+1], xv.y, ak); av = fmaf(wv[d4*4+1], xv.y, av);
            aq = fmaf(wq[d4*4+2], xv.z, aq); ak = fmaf(wk[d4*4+2], xv.z, ak); av = fmaf(wv[d4*4+2], xv.z, av);
            aq = fmaf(wq[d4*4+3], xv.w, aq); ak = fmaf(wk[d4*4+3], xv.w, ak); av = fmaf(wv[d4*4+3], xv.w, av);
        }
        const size_t o = (size_t)(n0 + s) * 256 + t;   // t == h*64+e
        q[o] = f2bf(aq);
        k[o] = f2bf(ak);
        v[o] = f2bf(av);
    }
}

// ---------------- CSR build ----------------
__global__ void hist_kernel(const int* __restrict__ idx_i, int* __restrict__ counts) {
    int e = blockIdx.x * 256 + threadIdx.x;    // 3125*256 == 800000 exactly
    atomicAdd(&counts[idx_i[e]], 1);
}

__global__ void scan_kernel(const int* __restrict__ counts, int* __restrict__ offsets, int n) {
    __shared__ int s[1024];
    const int t = threadIdx.x;
    int carry = 0;
    for (int base = 0; base < n; base += 1024) {
        int val = (base + t < n) ? counts[base + t] : 0;
        s[t] = val;
        __syncthreads();
        for (int off = 1; off < 1024; off <<= 1) {
            int add = (t >= off) ? s[t - off] : 0;
            __syncthreads();
            s[t] += add;
            __syncthreads();
        }
        if (base + t < n) offsets[base + t] = carry + s[t] - val;  // exclusive
        int tot = s[1023];
        __syncthreads();
        carry += tot;
    }
    if (t == 0) offsets[n] = carry;
}

__global__ void scatter_kernel(const int* __restrict__ idx_i, int* __restrict__ cursor,
                               int* __restrict__ el) {
    int e = blockIdx.x * 256 + threadIdx.x;
    int pos = atomicAdd(&cursor[idx_i[e]], 1);
    el[pos] = e;
}

// ---------------- Phase 1: per-(edge,head) alpha, edge-parallel, shuffle-free -----
// thread = one (edge, head). Private 64-d triple-product dot, fully unrolled.
// aphi[e*4+h] = phi[e]/8 * sum_d q[i,h,d]*w[e,h,d]*k[j,h,d]
__global__ __launch_bounds__(256) void alpha_kernel(
    const float* __restrict__ w_ij,
    const int* __restrict__ idx_i, const int* __restrict__ idx_j,
    const float* __restrict__ phi,
    const ushort_t* __restrict__ q, const ushort_t* __restrict__ kk,
    float* __restrict__ aphi)
{
    const int gid = blockIdx.x * 256 + threadIdx.x;   // 12500 * 256 == 3,200,000
    const int e = gid >> 2;
    const int h = gid & 3;
    const int i = idx_i[e];
    const int j = idx_j[e];

    const float4* wr = (const float4*)(w_ij + (size_t)e * 256 + h * 64);
    const uint4*  qr = (const uint4*)(q + (size_t)i * 256 + h * 64);
    const uint4*  kr = (const uint4*)(kk + (size_t)j * 256 + h * 64);

    float acc = 0.f;
#pragma unroll
    for (int c = 0; c < 8; ++c) {        // 8 chunks x 8 dims
        float4 w0 = wr[c * 2];
        float4 w1 = wr[c * 2 + 1];
        uint4 qv = qr[c];
        uint4 kv = kr[c];
        acc = fmaf(w0.x, bfu(qv.x & 0xffffu) * bfu(kv.x & 0xffffu), acc);
        acc = fmaf(w0.y, bfu(qv.x >> 16)     * bfu(kv.x >> 16),     acc);
        acc = fmaf(w0.z, bfu(qv.y & 0xffffu) * bfu(kv.y & 0xffffu), acc);
        acc = fmaf(w0.w, bfu(qv.y >> 16)     * bfu(kv.y >> 16),     acc);
        acc = fmaf(w1.x, bfu(qv.z & 0xffffu) * bfu(kv.z & 0xffffu), acc);
        acc = fmaf(w1.y, bfu(qv.z >> 16)     * bfu(kv.z >> 16),     acc);
        acc = fmaf(w1.z, bfu(qv.w & 0xffffu) * bfu(kv.w & 0xffffu), acc);
        acc = fmaf(w1.w, bfu(qv.w >> 16)     * bfu(kv.w >> 16),     acc);
    }
    aphi[gid] = acc * 0.125f * phi[e];
}

// ---------------- Phase 2: node-parallel weighted scatter, no shuffles ------------
// block = node, t = h*64+d. Inner loop: one v-gather + one fma per edge per lane,
// manually unrolled x4 so four independent gathers are in flight.
__global__ __launch_bounds__(256) void scatter2_kernel(
    const int* __restrict__ idx_j, const float* __restrict__ aphi,
    const ushort_t* __restrict__ vv,
    const int* __restrict__ offsets, const int* __restrict__ el,
    float* __restrict__ out)
{
    const int n = blockIdx.x;
    const int t = threadIdx.x;
    const int h = t >> 6;
    const int s0 = offsets[n], s1 = offsets[n + 1];

    __shared__ int   ej[256];
    __shared__ float ap[256][4];

    float acc = 0.f;
    for (int base = s0; base < s1; base += 256) {
        int cnt = min(256, s1 - base);
        if (t < cnt) {
            int e = el[base + t];
            ej[t] = idx_j[e];
            float4 a4 = ((const float4*)aphi)[e];
            ap[t][0] = a4.x; ap[t][1] = a4.y; ap[t][2] = a4.z; ap[t][3] = a4.w;
        }
        __syncthreads();
        int i = 0;
        for (; i + 4 <= cnt; i += 4) {
            int j0 = ej[i], j1 = ej[i + 1], j2 = ej[i + 2], j3 = ej[i + 3];
            float a0 = ap[i][h], a1 = ap[i + 1][h], a2 = ap[i + 2][h], a3 = ap[i + 3][h];
            float v0 = bfu(vv[(size_t)j0 * 256 + t]);
            float v1 = bfu(vv[(size_t)j1 * 256 + t]);
            float v2 = bfu(vv[(size_t)j2 * 256 + t]);
            float v3 = bfu(vv[(size_t)j3 * 256 + t]);
            acc = fmaf(a0, v0, acc);
            acc = fmaf(a1, v1, acc);
            acc = fmaf(a2, v2, acc);
            acc = fmaf(a3, v3, acc);
        }
        for (; i < cnt; ++i) {
            acc = fmaf(ap[i][h], bfu(vv[(size_t)ej[i] * 256 + t]), acc);
        }
        __syncthreads();
    }
    out[(size_t)n * 256 + t] = acc;
}

// ---------------- launch ----------------
extern "C" void kernel_launch(void* const* d_in, const int* in_sizes, int n_in,
                              void* d_out, int out_size, void* d_ws, size_t ws_size,
                              hipStream_t stream) {
    const float* x    = (const float*)d_in[0];
    const float* w_ij = (const float*)d_in[1];
    const int* idx_i  = (const int*)d_in[2];
    const int* idx_j  = (const int*)d_in[3];
    const float* phi  = (const float*)d_in[4];
    const float* Wq   = (const float*)d_in[5];
    const float* Wk   = (const float*)d_in[6];
    const float* Wv   = (const float*)d_in[7];
    float* out = (float*)d_out;

    char* ws = (char*)d_ws;
    ushort_t* q   = (ushort_t*)(ws + 0);           // 25.6 MB
    ushort_t* k   = (ushort_t*)(ws + 25600000);    // 25.6 MB
    ushort_t* v   = (ushort_t*)(ws + 51200000);    // 25.6 MB
    int* counts   = (int*)(ws + 76800000);         // 200 KB
    int* offsets  = (int*)(ws + 77000192);         // 200 KB (+1 entry)
    int* cursor   = (int*)(ws + 77200896);         // 200 KB
    int* el       = (int*)(ws + 77401088);         // 3.2 MB
    float* aphi   = (float*)(ws + 80601088);       // 12.8 MB (E x 4 fp32)

    hipMemsetAsync(counts, 0, N_NODES * sizeof(int), stream);
    proj_kernel<<<6250, 256, 0, stream>>>(x, Wq, Wk, Wv, q, k, v);
    hist_kernel<<<3125, 256, 0, stream>>>(idx_i, counts);
    scan_kernel<<<1, 1024, 0, stream>>>(counts, offsets, N_NODES);
    hipMemcpyAsync(cursor, offsets, N_NODES * sizeof(int), hipMemcpyDeviceToDevice, stream);
    scatter_kernel<<<3125, 256, 0, stream>>>(idx_i, cursor, el);
    alpha_kernel<<<12500, 256, 0, stream>>>(w_ij, idx_i, idx_j, phi, q, k, aphi);
    scatter2_kernel<<<N_NODES, 256, 0, stream>>>(idx_j, aphi, v, offsets, el, out);
}